// Round 1
// baseline (27350.400 us; speedup 1.0000x reference)
//
#include <hip/hip_runtime.h>
#include <math.h>

#define BDIM 1024
#define DDIM 512
#define VDIM 128
#define TDIM 201
#define FD   2048            // 4*D
#define NC   2176            // FD + V
#define LN_EPS 1e-5f

// ws layout in floats
#define OFF_H   0            // B*D      h state
#define OFF_C   524288       // B*D      c state
#define OFF_CTX 1048576      // B*D      context (constant across steps)
#define OFF_E   1572864      // V*FD     E = embed @ W_ih^T + b_ih + b_hh
#define OFF_CP  1835008      // B*V      ctx @ proj^T
#define OFF_LC  1966080      // B*V      current logits (for argmax)
#define OFF_G   2097152      // B*FD     raw gates (before E add)
// total = 4194304 floats = 16 MiB

// ---------------------------------------------------------------------------
// init: LayerNorm(pooled) -> h0 ; c0 = 0 ; softmax(fm@wf) -> context
// attention softmax is shift-invariant => h@wh + attn_b term drops out;
// context is constant across all T steps.
// ---------------------------------------------------------------------------
__global__ void k_init(const float* __restrict__ fm, const float* __restrict__ pooled,
                       const float* __restrict__ gamma, const float* __restrict__ beta,
                       const float* __restrict__ attn_w, float* __restrict__ ws)
{
    int b = blockIdx.x;
    int t = threadIdx.x;                 // 256 threads
    __shared__ float red[256];
    __shared__ float s_sc[49];
    __shared__ float s_aw[49];

    const float* prow = pooled + (size_t)b * DDIM;
    float x0 = prow[t], x1 = prow[t + 256];
    red[t] = x0 + x1;
    __syncthreads();
    for (int s = 128; s > 0; s >>= 1) { if (t < s) red[t] += red[t + s]; __syncthreads(); }
    float mu = red[0] * (1.0f / DDIM);
    __syncthreads();
    float d0 = x0 - mu, d1 = x1 - mu;
    red[t] = d0 * d0 + d1 * d1;
    __syncthreads();
    for (int s = 128; s > 0; s >>= 1) { if (t < s) red[t] += red[t + s]; __syncthreads(); }
    float rstd = rsqrtf(red[0] * (1.0f / DDIM) + LN_EPS);

    float* h = ws + OFF_H + (size_t)b * DDIM;
    float* c = ws + OFF_C + (size_t)b * DDIM;
    h[t]       = d0 * rstd * gamma[t]       + beta[t];
    h[t + 256] = d1 * rstd * gamma[t + 256] + beta[t + 256];
    c[t] = 0.0f;
    c[t + 256] = 0.0f;

    // scores[k] = sum_d fm[b,d,k] * wf[d]   (fm layout: (B, D, 49))
    if (t < 49) {
        const float* base = fm + (size_t)b * DDIM * 49 + t;
        float acc = 0.0f;
        for (int d = 0; d < DDIM; ++d) acc += base[(size_t)d * 49] * attn_w[d];
        s_sc[t] = acc;
    }
    __syncthreads();
    if (t == 0) {
        float mx = s_sc[0];
        for (int k = 1; k < 49; ++k) mx = fmaxf(mx, s_sc[k]);
        float sum = 0.0f;
        for (int k = 0; k < 49; ++k) { float e = expf(s_sc[k] - mx); s_aw[k] = e; sum += e; }
        float inv = 1.0f / sum;
        for (int k = 0; k < 49; ++k) s_aw[k] *= inv;
    }
    __syncthreads();

    float* ctx = ws + OFF_CTX + (size_t)b * DDIM;
    for (int d = t; d < DDIM; d += 256) {
        const float* base = fm + ((size_t)b * DDIM + d) * 49;
        float acc = 0.0f;
        for (int k = 0; k < 49; ++k) acc += s_aw[k] * base[k];
        ctx[d] = acc;
    }
}

// ---------------------------------------------------------------------------
// E[v, n] = sum_d embed[v,d] * W_ih[n,d] + b_ih[n] + b_hh[n]   (128 x 2048)
// one block per output column n; W row staged in LDS (coalesced), 128
// threads each handle one v streaming the (L2-resident) embed row.
// ---------------------------------------------------------------------------
__global__ void k_E(const float* __restrict__ embed, const float* __restrict__ W_ih,
                    const float* __restrict__ b_ih, const float* __restrict__ b_hh,
                    float* __restrict__ ws)
{
    int n = blockIdx.x;
    int t = threadIdx.x;                 // 256 threads
    __shared__ float wrow[DDIM];
    wrow[t]       = W_ih[(size_t)n * DDIM + t];
    wrow[t + 256] = W_ih[(size_t)n * DDIM + t + 256];
    __syncthreads();
    if (t < VDIM) {
        const float* er = embed + (size_t)t * DDIM;
        float acc = 0.0f;
        for (int d = 0; d < DDIM; ++d) acc += er[d] * wrow[d];
        ws[OFF_E + (size_t)t * FD + n] = acc + b_ih[n] + b_hh[n];
    }
}

// ---------------------------------------------------------------------------
// ctxproj[b, v] = sum_d ctx[b,d] * proj_w[v,d]
// ---------------------------------------------------------------------------
__global__ void k_cp(const float* __restrict__ proj_w, float* __restrict__ ws)
{
    int b = blockIdx.x;
    int t = threadIdx.x;                 // 128 threads, one per v
    __shared__ float crow[DDIM];
    const float* ctx = ws + OFF_CTX + (size_t)b * DDIM;
    for (int d = t; d < DDIM; d += 128) crow[d] = ctx[d];
    __syncthreads();
    const float* pr = proj_w + (size_t)t * DDIM;
    float acc = 0.0f;
    for (int d = 0; d < DDIM; ++d) acc += crow[d] * pr[d];
    ws[OFF_CP + (size_t)b * VDIM + t] = acc;
}

// ---------------------------------------------------------------------------
// Combined per-step GEMM:  C = (h + ctx) @ [W_hh^T | proj_w^T]
//   cols [0,2048): raw gates for this step -> ws gates buffer
//   cols [2048,2176): (h+ctx)@proj^T -> logits of PREVIOUS step after
//                     subtracting ctxproj and adding proj_b -> d_out + LC buf
// 64 threads/block, 64x64 tile, 8x8 micro-tile, BK=32.
// LDS padded to stride 68 floats: keeps float4 reads 16B-aligned and
// bank aliasing <= 2-way (free per m136).
// ---------------------------------------------------------------------------
#define BM 64
#define BN 64
#define BK 32

__global__ __launch_bounds__(64) void k_gemm(
        const float* __restrict__ W_hh, const float* __restrict__ proj_w,
        const float* __restrict__ proj_b, float* __restrict__ ws,
        float* __restrict__ out, int colTileOff, int tout)
{
    int ct = blockIdx.x + colTileOff;    // 0..33
    int rt = blockIdx.y;                 // 0..15
    int n0 = ct * BN;
    int b0 = rt * BM;
    int tid = threadIdx.x;

    __shared__ float As[BK][BM + 4];
    __shared__ float Bs[BK][BN + 4];

    const float* h   = ws + OFF_H;
    const float* ctx = ws + OFF_CTX;
    bool isLogit = (n0 >= FD);
    const float* wsrc = isLogit ? (proj_w + (size_t)(n0 - FD) * DDIM)
                                : (W_hh + (size_t)n0 * DDIM);

    float acc[8][8];
#pragma unroll
    for (int i = 0; i < 8; ++i)
#pragma unroll
        for (int j = 0; j < 8; ++j) acc[i][j] = 0.0f;

    int ty = tid >> 3, tx = tid & 7;

    for (int k0 = 0; k0 < DDIM; k0 += BK) {
        // stage A (h+ctx rows) and B (weight rows) tiles, transposed in LDS
#pragma unroll
        for (int i = 0; i < 8; ++i) {
            int fidx = i * 64 + tid;     // 0..511 float4 slots
            int kk4 = fidx & 7;          // float4 index within BK
            int rr  = fidx >> 3;         // row/col 0..63
            size_t goff = (size_t)rr * DDIM + k0 + kk4 * 4;
            float4 hv = *(const float4*)(h + (size_t)(b0) * DDIM + goff);
            float4 cv = *(const float4*)(ctx + (size_t)(b0) * DDIM + goff);
            As[kk4 * 4 + 0][rr] = hv.x + cv.x;
            As[kk4 * 4 + 1][rr] = hv.y + cv.y;
            As[kk4 * 4 + 2][rr] = hv.z + cv.z;
            As[kk4 * 4 + 3][rr] = hv.w + cv.w;
            float4 wv = *(const float4*)(wsrc + goff);
            Bs[kk4 * 4 + 0][rr] = wv.x;
            Bs[kk4 * 4 + 1][rr] = wv.y;
            Bs[kk4 * 4 + 2][rr] = wv.z;
            Bs[kk4 * 4 + 3][rr] = wv.w;
        }
        __syncthreads();
#pragma unroll 4
        for (int kk = 0; kk < BK; ++kk) {
            float a[8], bb[8];
            *(float4*)(a)      = *(const float4*)&As[kk][ty * 8];
            *(float4*)(a + 4)  = *(const float4*)&As[kk][ty * 8 + 4];
            *(float4*)(bb)     = *(const float4*)&Bs[kk][tx * 8];
            *(float4*)(bb + 4) = *(const float4*)&Bs[kk][tx * 8 + 4];
#pragma unroll
            for (int i = 0; i < 8; ++i)
#pragma unroll
                for (int j = 0; j < 8; ++j)
                    acc[i][j] = fmaf(a[i], bb[j], acc[i][j]);
        }
        __syncthreads();
    }

    if (!isLogit) {
        float* g = ws + OFF_G;
#pragma unroll
        for (int i = 0; i < 8; ++i) {
            int b = b0 + ty * 8 + i;
            float* dst = g + (size_t)b * FD + n0 + tx * 8;
            *(float4*)dst       = make_float4(acc[i][0], acc[i][1], acc[i][2], acc[i][3]);
            *(float4*)(dst + 4) = make_float4(acc[i][4], acc[i][5], acc[i][6], acc[i][7]);
        }
    } else {
        int v0 = n0 - FD + tx * 8;
#pragma unroll
        for (int i = 0; i < 8; ++i) {
            int b = b0 + ty * 8 + i;
#pragma unroll
            for (int j = 0; j < 8; ++j) {
                int v = v0 + j;
                float lg = acc[i][j] - ws[OFF_CP + (size_t)b * VDIM + v] + proj_b[v];
                if (tout >= 0) {
                    out[((size_t)b * VDIM + v) * TDIM + tout] = lg;
                    ws[OFF_LC + (size_t)b * VDIM + v] = lg;
                }
            }
        }
    }
}

// ---------------------------------------------------------------------------
// per-row: argmax(prev logits) -> embedding-GEMM gather E[id]; LSTM pointwise
//   c = sig(f)*c + sig(i)*tanh(g) ; h = sig(o)*tanh(c)
// argmax scans ascending with strict > : matches jnp.argmax first-index ties.
// ---------------------------------------------------------------------------
__global__ void k_point(float* __restrict__ ws, const int* __restrict__ sos_p,
                        int doArgmax)
{
    int b = blockIdx.x;
    int t = threadIdx.x;                 // 256 threads
    __shared__ float s_v[VDIM];
    __shared__ int s_id;

    if (doArgmax) {
        if (t < VDIM) s_v[t] = ws[OFF_LC + (size_t)b * VDIM + t];
        __syncthreads();
        if (t == 0) {
            float best = s_v[0];
            int bi = 0;
            for (int v = 1; v < VDIM; ++v)
                if (s_v[v] > best) { best = s_v[v]; bi = v; }
            s_id = bi;
        }
    } else {
        if (t == 0) s_id = sos_p[0];
    }
    __syncthreads();
    int id = s_id;

    const float* g = ws + OFF_G + (size_t)b * FD;
    const float* E = ws + OFF_E + (size_t)id * FD;
    float* c = ws + OFF_C + (size_t)b * DDIM;
    float* h = ws + OFF_H + (size_t)b * DDIM;

    for (int d = t; d < DDIM; d += 256) {
        float gi = g[d]            + E[d];
        float gf = g[d + DDIM]     + E[d + DDIM];
        float gg = g[d + 2 * DDIM] + E[d + 2 * DDIM];
        float go = g[d + 3 * DDIM] + E[d + 3 * DDIM];
        float cv = c[d];
        float si = 1.0f / (1.0f + expf(-gi));
        float sf = 1.0f / (1.0f + expf(-gf));
        float so = 1.0f / (1.0f + expf(-go));
        float cn = sf * cv + si * tanhf(gg);
        c[d] = cn;
        h[d] = so * tanhf(cn);
    }
}

extern "C" void kernel_launch(void* const* d_in, const int* in_sizes, int n_in,
                              void* d_out, int out_size, void* d_ws, size_t ws_size,
                              hipStream_t stream)
{
    const float* fm     = (const float*)d_in[0];
    const float* pooled = (const float*)d_in[1];
    const float* gamma  = (const float*)d_in[2];
    const float* beta   = (const float*)d_in[3];
    const float* W_ih   = (const float*)d_in[4];
    const float* W_hh   = (const float*)d_in[5];
    const float* b_ih   = (const float*)d_in[6];
    const float* b_hh   = (const float*)d_in[7];
    const float* embed  = (const float*)d_in[8];
    const float* attn_w = (const float*)d_in[9];
    // d_in[10] = attn_b : provably unused (softmax shift invariance)
    const float* proj_w = (const float*)d_in[11];
    const float* proj_b = (const float*)d_in[12];
    const int*   sos_p  = (const int*)d_in[13];

    float* ws  = (float*)d_ws;
    float* out = (float*)d_out;

    k_init<<<BDIM, 256, 0, stream>>>(fm, pooled, gamma, beta, attn_w, ws);
    k_E<<<FD, 256, 0, stream>>>(embed, W_ih, b_ih, b_hh, ws);
    k_cp<<<BDIM, 128, 0, stream>>>(proj_w, ws);

    // tick 0: gates only (col tiles 0..31), no logits yet
    k_gemm<<<dim3(32, 16), 64, 0, stream>>>(W_hh, proj_w, proj_b, ws, out, 0, -1);
    k_point<<<BDIM, 256, 0, stream>>>(ws, sos_p, 0);

    // ticks 1..200: full GEMM -> logits of step tau-1 + gates of step tau
    for (int tau = 1; tau <= 200; ++tau) {
        k_gemm<<<dim3(34, 16), 64, 0, stream>>>(W_hh, proj_w, proj_b, ws, out, 0, tau - 1);
        k_point<<<BDIM, 256, 0, stream>>>(ws, sos_p, 1);
    }

    // tick 201: logits of step 200 only (col tiles 32..33)
    k_gemm<<<dim3(2, 16), 64, 0, stream>>>(W_hh, proj_w, proj_b, ws, out, 32, 200);
}

// Round 3
// 6427.072 us; speedup vs baseline: 4.2555x; 4.2555x over previous
//
#include <hip/hip_runtime.h>
#include <math.h>

#define BDIM 1024
#define DDIM 512
#define VDIM 128
#define TDIM 201
#define FD   2048            // 4*D
#define LN_EPS 1e-5f
#define LOSCALE 4096.0f
#define INV_LOSCALE (1.0f/4096.0f)

// ws layout in floats (total 5,308,416 floats = 20.25 MiB)
#define OFF_C   0            // B*D      c state
#define OFF_CTX 524288       // B*D      context (constant across steps)
#define OFF_E   1048576      // V*FD     E = embed @ W_ih^T + b_ih + b_hh
#define OFF_CP  1310720      // B*V      ctx @ proj^T
#define OFF_LC  1441792      // B*V      current logits (for argmax)
#define OFF_G   1572864      // B*FD     raw gates (before E add)
#define OFF_AHI 3670016      // 64*16*64*8 f16 = 262144 floats: A hi frags
#define OFF_ALO 3932160      // A lo frags (scaled by 4096)
#define OFF_BHI 4194304      // 136*16*64*8 f16 = 557056 floats: B hi frags
#define OFF_BLO 4751360      // B lo frags (scaled by 4096)

typedef _Float16 v8hf __attribute__((ext_vector_type(8)));
typedef float    v4f  __attribute__((ext_vector_type(4)));

// Fragment-major layouts (16x16x32 f16 MFMA):
//   A operand: lane l holds A[m = mt*16 + (l&15)][k = kt*32 + (l>>4)*8 + j]
//     Afrag[((mt*16 + kt)*64 + l)*8 + j]
//   B operand: lane l holds W[n = nt*16 + (l&15)][k = kt*32 + (l>>4)*8 + j]
//   C/D: col = lane&15, row = (lane>>4)*4 + reg   (m89/m91 verified)
//
// Precision: x = hi + lo/4096 with |x - hi - lo/4096| <= 2^-24|x|.
// Products: hi*hi -> acc1 ; hi*lo + lo*hi -> acc2 ; result = acc1 + acc2/4096.
// Dropped lo*lo term ~2^-24 — at the fp32 accumulate-rounding floor.
// Scaling keeps lo in fp16 NORMAL range (raw lo of 0.05-scale weights would
// be subnormal -> MFMA flush hazard).

__device__ __forceinline__ void split_write(float x, _Float16* hiArr, _Float16* loArr,
                                            int row, int k)
{
    _Float16 hi = (_Float16)x;
    _Float16 lo = (_Float16)((x - (float)hi) * LOSCALE);
    int lane = (row & 15) | (((k >> 3) & 3) << 4);
    size_t idx = ((size_t)((row >> 4) * 16 + (k >> 5)) * 64 + lane) * 8 + (k & 7);
    hiArr[idx] = hi;
    loArr[idx] = lo;
}

// ---------------------------------------------------------------------------
// init: LayerNorm(pooled) -> h0 ; c0 = 0 ; softmax(fm@wf) -> context ;
// write A-fragments of (h0 + ctx). Softmax shift-invariance kills the
// h@wh + attn_b term, so context is constant across all T steps.
// ---------------------------------------------------------------------------
__global__ void k_init(const float* __restrict__ fm, const float* __restrict__ pooled,
                       const float* __restrict__ gamma, const float* __restrict__ beta,
                       const float* __restrict__ attn_w, float* __restrict__ ws)
{
    int b = blockIdx.x;
    int t = threadIdx.x;                 // 256 threads
    __shared__ float red[256];
    __shared__ float s_sc[49];
    __shared__ float s_aw[49];
    __shared__ float s_ctx[DDIM];

    const float* prow = pooled + (size_t)b * DDIM;
    float x0 = prow[t], x1 = prow[t + 256];
    red[t] = x0 + x1;
    __syncthreads();
    for (int s = 128; s > 0; s >>= 1) { if (t < s) red[t] += red[t + s]; __syncthreads(); }
    float mu = red[0] * (1.0f / DDIM);
    __syncthreads();
    float d0 = x0 - mu, d1 = x1 - mu;
    red[t] = d0 * d0 + d1 * d1;
    __syncthreads();
    for (int s = 128; s > 0; s >>= 1) { if (t < s) red[t] += red[t + s]; __syncthreads(); }
    float rstd = rsqrtf(red[0] * (1.0f / DDIM) + LN_EPS);

    float h0 = d0 * rstd * gamma[t]       + beta[t];
    float h1 = d1 * rstd * gamma[t + 256] + beta[t + 256];

    float* c = ws + OFF_C + (size_t)b * DDIM;
    c[t] = 0.0f;
    c[t + 256] = 0.0f;

    // scores[k] = sum_d fm[b,d,k] * wf[d]   (fm layout: (B, D, 49))
    if (t < 49) {
        const float* base = fm + (size_t)b * DDIM * 49 + t;
        float acc = 0.0f;
        for (int d = 0; d < DDIM; ++d) acc += base[(size_t)d * 49] * attn_w[d];
        s_sc[t] = acc;
    }
    __syncthreads();
    if (t == 0) {
        float mx = s_sc[0];
        for (int k = 1; k < 49; ++k) mx = fmaxf(mx, s_sc[k]);
        float sum = 0.0f;
        for (int k = 0; k < 49; ++k) { float e = expf(s_sc[k] - mx); s_aw[k] = e; sum += e; }
        float inv = 1.0f / sum;
        for (int k = 0; k < 49; ++k) s_aw[k] *= inv;
    }
    __syncthreads();

    float* ctx = ws + OFF_CTX + (size_t)b * DDIM;
    for (int d = t; d < DDIM; d += 256) {
        const float* base = fm + ((size_t)b * DDIM + d) * 49;
        float acc = 0.0f;
        for (int k = 0; k < 49; ++k) acc += s_aw[k] * base[k];
        ctx[d] = acc;
        s_ctx[d] = acc;
    }
    __syncthreads();

    _Float16* Ahi = (_Float16*)(ws + OFF_AHI);
    _Float16* Alo = (_Float16*)(ws + OFF_ALO);
    split_write(h0 + s_ctx[t],       Ahi, Alo, b, t);
    split_write(h1 + s_ctx[t + 256], Ahi, Alo, b, t + 256);
}

// ---------------------------------------------------------------------------
// E[v, n] = sum_d embed[v,d] * W_ih[n,d] + b_ih[n] + b_hh[n]   (128 x 2048)
// ---------------------------------------------------------------------------
__global__ void k_E(const float* __restrict__ embed, const float* __restrict__ W_ih,
                    const float* __restrict__ b_ih, const float* __restrict__ b_hh,
                    float* __restrict__ ws)
{
    int n = blockIdx.x;
    int t = threadIdx.x;                 // 256 threads
    __shared__ float wrow[DDIM];
    wrow[t]       = W_ih[(size_t)n * DDIM + t];
    wrow[t + 256] = W_ih[(size_t)n * DDIM + t + 256];
    __syncthreads();
    if (t < VDIM) {
        const float* er = embed + (size_t)t * DDIM;
        float acc = 0.0f;
        for (int d = 0; d < DDIM; ++d) acc += er[d] * wrow[d];
        ws[OFF_E + (size_t)t * FD + n] = acc + b_ih[n] + b_hh[n];
    }
}

// ---------------------------------------------------------------------------
// ctxproj[b, v] = sum_d ctx[b,d] * proj_w[v,d]
// ---------------------------------------------------------------------------
__global__ void k_cp(const float* __restrict__ proj_w, float* __restrict__ ws)
{
    int b = blockIdx.x;
    int t = threadIdx.x;                 // 128 threads, one per v
    __shared__ float crow[DDIM];
    const float* ctx = ws + OFF_CTX + (size_t)b * DDIM;
    for (int d = t; d < DDIM; d += 128) crow[d] = ctx[d];
    __syncthreads();
    const float* pr = proj_w + (size_t)t * DDIM;
    float acc = 0.0f;
    for (int d = 0; d < DDIM; ++d) acc += crow[d] * pr[d];
    ws[OFF_CP + (size_t)b * VDIM + t] = acc;
}

// ---------------------------------------------------------------------------
// One-time: convert [W_hh | proj_w] (2176 x 512) to fragment-major f16 hi/lo
// ---------------------------------------------------------------------------
__global__ void k_bsetup(const float* __restrict__ W_hh, const float* __restrict__ proj_w,
                         float* __restrict__ ws)
{
    int n = blockIdx.x;                  // 0..2175
    int t = threadIdx.x;                 // 256
    const float* src = (n < FD) ? (W_hh + (size_t)n * DDIM)
                                : (proj_w + (size_t)(n - FD) * DDIM);
    _Float16* Bhi = (_Float16*)(ws + OFF_BHI);
    _Float16* Blo = (_Float16*)(ws + OFF_BLO);
    for (int k = t; k < DDIM; k += 256)
        split_write(src[k], Bhi, Blo, n, k);
}

// ---------------------------------------------------------------------------
// Per-step GEMM via scaled-split-f16 MFMA:  C = (h+ctx) @ [W_hh^T | proj_w^T]
//   acc1 += hi*hi ; acc2 += hi*lo' + lo'*hi ; C = acc1 + acc2/4096
// grid (16 row-tiles, N col-tiles), 256 thr = 4 waves; wave w handles a
// 16-row band x 64 cols. No LDS, no barriers: fragments load straight from
// fragment-major global arrays (coalesced dwordx4; all 4 waves of a block
// read the same B fragments -> L1 serves 3/4 of B traffic).
// ---------------------------------------------------------------------------
__global__ __launch_bounds__(256) void k_gemm(
        const float* __restrict__ proj_b, float* __restrict__ ws,
        float* __restrict__ out, int colTileOff, int tout)
{
    int rt = blockIdx.x;                 // 0..15  (x fastest: same-ct blocks adjacent)
    int ct = blockIdx.y + colTileOff;    // 0..33
    int tid = threadIdx.x;
    int w = tid >> 6, lane = tid & 63;
    int mt  = rt * 4 + w;                // this wave's mtile (0..63)
    int ntb = ct * 4;                    // first of 4 ntiles (0..135)

    const v8hf* Ah = (const v8hf*)(ws + OFF_AHI);
    const v8hf* Al = (const v8hf*)(ws + OFF_ALO);
    const v8hf* Bh = (const v8hf*)(ws + OFF_BHI);
    const v8hf* Bl = (const v8hf*)(ws + OFF_BLO);

    v4f acc1[4], acc2[4];
#pragma unroll
    for (int nt = 0; nt < 4; ++nt) {
        acc1[nt] = (v4f){0.f, 0.f, 0.f, 0.f};
        acc2[nt] = (v4f){0.f, 0.f, 0.f, 0.f};
    }

    int aBase = mt * 16;                 // + kt, then *64 + lane
    v8hf ah = Ah[(aBase + 0) * 64 + lane];
    v8hf al = Al[(aBase + 0) * 64 + lane];
    v8hf bh[4], bl[4];
#pragma unroll
    for (int nt = 0; nt < 4; ++nt) {
        bh[nt] = Bh[((ntb + nt) * 16 + 0) * 64 + lane];
        bl[nt] = Bl[((ntb + nt) * 16 + 0) * 64 + lane];
    }

#pragma unroll
    for (int kt = 0; kt < 16; ++kt) {
        v8hf nah, nal, nbh[4], nbl[4];
        if (kt < 15) {
            int k1 = kt + 1;
            nah = Ah[(aBase + k1) * 64 + lane];
            nal = Al[(aBase + k1) * 64 + lane];
#pragma unroll
            for (int nt = 0; nt < 4; ++nt) {
                nbh[nt] = Bh[((ntb + nt) * 16 + k1) * 64 + lane];
                nbl[nt] = Bl[((ntb + nt) * 16 + k1) * 64 + lane];
            }
        }
#pragma unroll
        for (int nt = 0; nt < 4; ++nt) {
            acc1[nt] = __builtin_amdgcn_mfma_f32_16x16x32_f16(ah, bh[nt], acc1[nt], 0, 0, 0);
            acc2[nt] = __builtin_amdgcn_mfma_f32_16x16x32_f16(ah, bl[nt], acc2[nt], 0, 0, 0);
            acc2[nt] = __builtin_amdgcn_mfma_f32_16x16x32_f16(al, bh[nt], acc2[nt], 0, 0, 0);
        }
        if (kt < 15) {
            ah = nah; al = nal;
#pragma unroll
            for (int nt = 0; nt < 4; ++nt) { bh[nt] = nbh[nt]; bl[nt] = nbl[nt]; }
        }
    }

    // Epilogue. C/D: col = lane&15, row = (lane>>4)*4 + reg
    int nloc = lane & 15;
    int mrow = mt * 16 + (lane >> 4) * 4;
    if (ntb < 128) {                     // gates tiles
        float* g = ws + OFF_G;
#pragma unroll
        for (int nt = 0; nt < 4; ++nt) {
            int n = (ntb + nt) * 16 + nloc;
#pragma unroll
            for (int r = 0; r < 4; ++r)
                g[(size_t)(mrow + r) * FD + n] = acc1[nt][r] + acc2[nt][r] * INV_LOSCALE;
        }
    } else {                             // logits tiles
#pragma unroll
        for (int nt = 0; nt < 4; ++nt) {
            int v = (ntb + nt) * 16 + nloc - FD;
#pragma unroll
            for (int r = 0; r < 4; ++r) {
                int b = mrow + r;
                float val = acc1[nt][r] + acc2[nt][r] * INV_LOSCALE;
                float lg = val - ws[OFF_CP + (size_t)b * VDIM + v] + proj_b[v];
                if (tout >= 0) {
                    out[((size_t)b * VDIM + v) * TDIM + tout] = lg;
                    ws[OFF_LC + (size_t)b * VDIM + v] = lg;
                }
            }
        }
    }
}

// ---------------------------------------------------------------------------
// per-row: argmax(prev logits) -> E[id] gather; LSTM pointwise; write the
// A-fragments (hi/lo f16 of h_new + ctx) for the next step's GEMM.
// argmax: ascending scan, strict > : matches jnp.argmax first-index ties.
// ---------------------------------------------------------------------------
__global__ void k_point(float* __restrict__ ws, const int* __restrict__ sos_p,
                        int doArgmax)
{
    int b = blockIdx.x;
    int t = threadIdx.x;                 // 256 threads
    __shared__ float s_v[VDIM];
    __shared__ int s_id;

    if (doArgmax) {
        if (t < VDIM) s_v[t] = ws[OFF_LC + (size_t)b * VDIM + t];
        __syncthreads();
        if (t == 0) {
            float best = s_v[0];
            int bi = 0;
            for (int v = 1; v < VDIM; ++v)
                if (s_v[v] > best) { best = s_v[v]; bi = v; }
            s_id = bi;
        }
    } else {
        if (t == 0) s_id = sos_p[0];
    }
    __syncthreads();
    int id = s_id;

    const float* g   = ws + OFF_G   + (size_t)b * FD;
    const float* E   = ws + OFF_E   + (size_t)id * FD;
    const float* ctx = ws + OFF_CTX + (size_t)b * DDIM;
    float* c = ws + OFF_C + (size_t)b * DDIM;
    _Float16* Ahi = (_Float16*)(ws + OFF_AHI);
    _Float16* Alo = (_Float16*)(ws + OFF_ALO);

    for (int d = t; d < DDIM; d += 256) {
        float gi = g[d]            + E[d];
        float gf = g[d + DDIM]     + E[d + DDIM];
        float gg = g[d + 2 * DDIM] + E[d + 2 * DDIM];
        float go = g[d + 3 * DDIM] + E[d + 3 * DDIM];
        float cv = c[d];
        float si = 1.0f / (1.0f + expf(-gi));
        float sf = 1.0f / (1.0f + expf(-gf));
        float so = 1.0f / (1.0f + expf(-go));
        float cn = sf * cv + si * tanhf(gg);
        c[d] = cn;
        float hn = so * tanhf(cn);
        split_write(hn + ctx[d], Ahi, Alo, b, d);
    }
}

extern "C" void kernel_launch(void* const* d_in, const int* in_sizes, int n_in,
                              void* d_out, int out_size, void* d_ws, size_t ws_size,
                              hipStream_t stream)
{
    const float* fm     = (const float*)d_in[0];
    const float* pooled = (const float*)d_in[1];
    const float* gamma  = (const float*)d_in[2];
    const float* beta   = (const float*)d_in[3];
    const float* W_ih   = (const float*)d_in[4];
    const float* W_hh   = (const float*)d_in[5];
    const float* b_ih   = (const float*)d_in[6];
    const float* b_hh   = (const float*)d_in[7];
    const float* embed  = (const float*)d_in[8];
    const float* attn_w = (const float*)d_in[9];
    // d_in[10] = attn_b : provably unused (softmax shift invariance)
    const float* proj_w = (const float*)d_in[11];
    const float* proj_b = (const float*)d_in[12];
    const int*   sos_p  = (const int*)d_in[13];

    float* ws  = (float*)d_ws;
    float* out = (float*)d_out;

    k_init<<<BDIM, 256, 0, stream>>>(fm, pooled, gamma, beta, attn_w, ws);
    k_E<<<FD, 256, 0, stream>>>(embed, W_ih, b_ih, b_hh, ws);
    k_cp<<<BDIM, 128, 0, stream>>>(proj_w, ws);
    k_bsetup<<<FD + VDIM, 256, 0, stream>>>(W_hh, proj_w, ws);

    // tick 0: gates only (col tiles 0..31), no logits yet
    k_gemm<<<dim3(16, 32), 256, 0, stream>>>(proj_b, ws, out, 0, -1);
    k_point<<<BDIM, 256, 0, stream>>>(ws, sos_p, 0);

    // ticks 1..200: full GEMM -> logits of step tau-1 + gates of step tau
    for (int tau = 1; tau <= 200; ++tau) {
        k_gemm<<<dim3(16, 34), 256, 0, stream>>>(proj_b, ws, out, 0, tau - 1);
        k_point<<<BDIM, 256, 0, stream>>>(ws, sos_p, 1);
    }

    // tick 201: logits of step 200 only (col tiles 32..33)
    k_gemm<<<dim3(16, 2), 256, 0, stream>>>(proj_b, ws, out, 32, 200);
}